// Round 4
// baseline (1904.700 us; speedup 1.0000x reference)
//
#include <hip/hip_runtime.h>
#include <hip/hip_bf16.h>

// TreeLSTMDoubleCell: N nodes, E edges (src->dst, dst sorted), H=X=128.
// Pipeline:
//   K0 pack:   W1,U1,W2,U2 [128,512] f32 -> transposed bf16 [512][128]; b1=bW1+bU1, b2=bW2+bU2
//   K1 segsum: mailboxes mh1(bf16), mc1(f32), mh2(bf16), mc2(f32) via sorted-dst binary search
//   K2 stage1: acc = x@W1 + mh1@U1 (bf16 MFMA 16x16x32, fp32 acc) + b1 -> gates -> h1n,c1n (+c1n bf16)
//   K3 stage2: acc = c1n@W2 + mh2@U2 + b2 -> gates -> h2n,c2n

#define H128 128

typedef __attribute__((ext_vector_type(8))) short s8b;   // 8 x bf16 bits
typedef __attribute__((ext_vector_type(4))) float f4x;   // MFMA accumulator
typedef __attribute__((ext_vector_type(4))) short sh4;   // 4 x bf16 bits

static __device__ __forceinline__ short f2bf(float f) {
  __hip_bfloat16 b = __float2bfloat16(f);
  return __builtin_bit_cast(short, b);
}
static __device__ __forceinline__ float sigf(float v) {
  return 1.0f / (1.0f + __expf(-v));
}

// ---------------- K0: pack weights (transpose to [col][k], bf16) + fold biases ----
__global__ void pack_weights(const float* __restrict__ W1, const float* __restrict__ U1,
                             const float* __restrict__ W2, const float* __restrict__ U2,
                             const float* __restrict__ bW1, const float* __restrict__ bU1,
                             const float* __restrict__ bW2, const float* __restrict__ bU2,
                             __hip_bfloat16* __restrict__ WT1, __hip_bfloat16* __restrict__ UT1,
                             __hip_bfloat16* __restrict__ WT2, __hip_bfloat16* __restrict__ UT2,
                             float* __restrict__ b1, float* __restrict__ b2) {
  int idx = blockIdx.x * 256 + threadIdx.x;
  if (idx < 4 * 65536) {
    int mat = idx >> 16;
    int rem = idx & 65535;
    int c = rem >> 7;      // 0..511 (output column)
    int k = rem & 127;     // 0..127 (reduction index)
    const float* S = (mat == 0) ? W1 : (mat == 1) ? U1 : (mat == 2) ? W2 : U2;
    __hip_bfloat16* D = (mat == 0) ? WT1 : (mat == 1) ? UT1 : (mat == 2) ? WT2 : UT2;
    D[c * 128 + k] = __float2bfloat16(S[k * 512 + c]);
  }
  if (idx < 512) {
    b1[idx] = bW1[idx] + bU1[idx];
    b2[idx] = bW2[idx] + bU2[idx];
  }
}

// ---------------- K1: segment-sum mailboxes (dst sorted; binary search; no atomics) ----
// 256 threads = 8 nodes/block; 32 lanes per node, float4 per lane (16B, G13).
__global__ __launch_bounds__(256) void segsum(
    const float* __restrict__ h1, const float* __restrict__ c1,
    const float* __restrict__ h2, const float* __restrict__ c2,
    const int* __restrict__ src, const int* __restrict__ dst, int E, int N,
    __hip_bfloat16* __restrict__ mh1, float* __restrict__ mc1,
    __hip_bfloat16* __restrict__ mh2, float* __restrict__ mc2) {
  const int node = blockIdx.x * 8 + (threadIdx.x >> 5);
  if (node >= N) return;
  const int f4 = threadIdx.x & 31;       // feature quad 0..31

  int lo = 0, hi = E;
  while (lo < hi) { int mid = (lo + hi) >> 1; if (dst[mid] < node) lo = mid + 1; else hi = mid; }
  const int e0 = lo;
  hi = E;
  while (lo < hi) { int mid = (lo + hi) >> 1; if (dst[mid] < node + 1) lo = mid + 1; else hi = mid; }
  const int e1 = lo;

  float4 sh1 = {0, 0, 0, 0}, sc1 = {0, 0, 0, 0}, sh2 = {0, 0, 0, 0}, sc2 = {0, 0, 0, 0};
  for (int e = e0; e < e1; ++e) {
    size_t s = (size_t)src[e] * H128 + f4 * 4;
    float4 a = *(const float4*)(h1 + s);
    float4 b = *(const float4*)(c1 + s);
    float4 c = *(const float4*)(h2 + s);
    float4 d = *(const float4*)(c2 + s);
    sh1.x += a.x; sh1.y += a.y; sh1.z += a.z; sh1.w += a.w;
    sc1.x += b.x; sc1.y += b.y; sc1.z += b.z; sc1.w += b.w;
    sh2.x += c.x; sh2.y += c.y; sh2.z += c.z; sh2.w += c.w;
    sc2.x += d.x; sc2.y += d.y; sc2.z += d.z; sc2.w += d.w;
  }
  size_t o = (size_t)node * H128 + f4 * 4;
  sh4 p1; p1[0] = f2bf(sh1.x); p1[1] = f2bf(sh1.y); p1[2] = f2bf(sh1.z); p1[3] = f2bf(sh1.w);
  sh4 p2; p2[0] = f2bf(sh2.x); p2[1] = f2bf(sh2.y); p2[2] = f2bf(sh2.z); p2[3] = f2bf(sh2.w);
  *(sh4*)(mh1 + o) = p1;
  *(sh4*)(mh2 + o) = p2;
  *(float4*)(mc1 + o) = sc1;
  *(float4*)(mc2 + o) = sc2;
}

// ---------------- K2/K3: fused dual-GEMM + gates ------------------------------------
// Block = 256 threads (4 waves) handles a 16-node strip; wave w covers colgroups {w, w+4}.
// acc[g] (g=0:i,1:o,2:u,3:f) = sum_k A1[row,k]*WT[g*128+n,k] + A2[row,k]*UT[g*128+n,k]
// MFMA 16x16x32 bf16: A lane(l): row=l&15, k=(l>>4)*8+j ; C/D: col=l&15, row=(l>>4)*4+r.
template <bool AF32>
__global__ __launch_bounds__(256) void stage(
    const void* __restrict__ A1v, const __hip_bfloat16* __restrict__ A2,
    const float* __restrict__ MC, const __hip_bfloat16* __restrict__ WT,
    const __hip_bfloat16* __restrict__ UT, const float* __restrict__ bias,
    float* __restrict__ outH, float* __restrict__ outC, __hip_bfloat16* __restrict__ outCb) {
  const int R = blockIdx.x * 16;
  const int l = threadIdx.x & 63;
  const int w = threadIdx.x >> 6;
  const int m = l & 15;
  const int kq = l >> 4;
  const int ko = kq * 8;

  s8b ax[4], ah[4];
  if (AF32) {
    const float* xr = (const float*)A1v + (size_t)(R + m) * H128 + ko;
#pragma unroll
    for (int kk = 0; kk < 4; kk++) {
      const float4* p = (const float4*)(xr + kk * 32);
      float4 u0 = p[0], u1 = p[1];
      s8b v;
      v[0] = f2bf(u0.x); v[1] = f2bf(u0.y); v[2] = f2bf(u0.z); v[3] = f2bf(u0.w);
      v[4] = f2bf(u1.x); v[5] = f2bf(u1.y); v[6] = f2bf(u1.z); v[7] = f2bf(u1.w);
      ax[kk] = v;
    }
  } else {
    const __hip_bfloat16* xr = (const __hip_bfloat16*)A1v + (size_t)(R + m) * H128 + ko;
#pragma unroll
    for (int kk = 0; kk < 4; kk++) ax[kk] = *(const s8b*)(xr + kk * 32);
  }
  {
    const __hip_bfloat16* hr = A2 + (size_t)(R + m) * H128 + ko;
#pragma unroll
    for (int kk = 0; kk < 4; kk++) ah[kk] = *(const s8b*)(hr + kk * 32);
  }

#pragma unroll
  for (int t = 0; t < 2; t++) {
    const int cg = w + 4 * t;
    const int n = cg * 16 + m;  // output column 0..127 (per gate block)
    f4x acc[4];
#pragma unroll
    for (int g = 0; g < 4; g++) { acc[g][0] = 0.f; acc[g][1] = 0.f; acc[g][2] = 0.f; acc[g][3] = 0.f; }
#pragma unroll
    for (int g = 0; g < 4; g++) {
      const s8b* wt = (const s8b*)(WT + (size_t)(g * 128 + n) * H128);
      const s8b* ut = (const s8b*)(UT + (size_t)(g * 128 + n) * H128);
#pragma unroll
      for (int kk = 0; kk < 4; kk++) {
        acc[g] = __builtin_amdgcn_mfma_f32_16x16x32_bf16(ax[kk], wt[kk * 4 + kq], acc[g], 0, 0, 0);
        acc[g] = __builtin_amdgcn_mfma_f32_16x16x32_bf16(ah[kk], ut[kk * 4 + kq], acc[g], 0, 0, 0);
      }
    }
    const float bi = bias[n], bo = bias[128 + n], bu = bias[256 + n], bff = bias[384 + n];
#pragma unroll
    for (int r = 0; r < 4; r++) {
      const size_t row = (size_t)R + kq * 4 + r;
      float pi = acc[0][r] + bi, po = acc[1][r] + bo, pu = acc[2][r] + bu, pf = acc[3][r] + bff;
      float gi = sigf(pi), go = sigf(po), gu = tanhf(pu), gf = sigf(pf);
      float cc = gi * gu + gf * MC[row * H128 + n];
      float hh = go * tanhf(cc);
      outH[row * H128 + n] = hh;
      outC[row * H128 + n] = cc;
      if (outCb) outCb[row * H128 + n] = __float2bfloat16(cc);
    }
  }
}

// ---------------- host launch --------------------------------------------------------
extern "C" void kernel_launch(void* const* d_in, const int* in_sizes, int n_in,
                              void* d_out, int out_size, void* d_ws, size_t ws_size,
                              hipStream_t stream) {
  const float* x   = (const float*)d_in[0];
  const float* h1  = (const float*)d_in[1];
  const float* c1  = (const float*)d_in[2];
  const float* h2  = (const float*)d_in[3];
  const float* c2  = (const float*)d_in[4];
  const float* W1  = (const float*)d_in[5];
  const float* bW1 = (const float*)d_in[6];
  const float* U1  = (const float*)d_in[7];
  const float* bU1 = (const float*)d_in[8];
  const float* W2  = (const float*)d_in[9];
  const float* bW2 = (const float*)d_in[10];
  const float* U2  = (const float*)d_in[11];
  const float* bU2 = (const float*)d_in[12];
  const int* src   = (const int*)d_in[13];
  const int* dst   = (const int*)d_in[14];

  const int N = in_sizes[1] / H128;   // 200000
  const int E = in_sizes[13];         // 800000
  const size_t NH = (size_t)N * H128;

  // workspace layout (bf16 region first, then f32 region)
  __hip_bfloat16* B = (__hip_bfloat16*)d_ws;
  __hip_bfloat16* WT1 = B;
  __hip_bfloat16* UT1 = B + 65536;
  __hip_bfloat16* WT2 = B + 131072;
  __hip_bfloat16* UT2 = B + 196608;
  __hip_bfloat16* mh1 = B + 262144;
  __hip_bfloat16* mh2 = mh1 + NH;
  __hip_bfloat16* c1b = mh2 + NH;
  float* F   = (float*)(c1b + NH);
  float* b1  = F;
  float* b2  = F + 512;
  float* mc1 = F + 1024;
  float* mc2 = mc1 + NH;

  float* out = (float*)d_out;
  float* h1n = out;
  float* c1n = out + NH;
  float* h2n = out + 2 * NH;
  float* c2n = out + 3 * NH;

  pack_weights<<<1024, 256, 0, stream>>>(W1, U1, W2, U2, bW1, bU1, bW2, bU2,
                                         WT1, UT1, WT2, UT2, b1, b2);
  segsum<<<(N + 7) / 8, 256, 0, stream>>>(h1, c1, h2, c2, src, dst, E, N,
                                          mh1, mc1, mh2, mc2);
  stage<true><<<N / 16, 256, 0, stream>>>((const void*)x, mh1, mc1, WT1, UT1, b1,
                                          h1n, c1n, c1b);
  stage<false><<<N / 16, 256, 0, stream>>>((const void*)c1b, mh2, mc2, WT2, UT2, b2,
                                           h2n, c2n, (/*no bf16 copy*/ __hip_bfloat16*)nullptr);
}